// Round 4
// baseline (1693.937 us; speedup 1.0000x reference)
//
#include <hip/hip_runtime.h>
#include <hip/hip_fp16.h>

#define NN 100000
#define NE 1600000

typedef __half half_t;

// ---------------- helpers ----------------

__device__ inline float2 load2(const float* p) {
    return *reinterpret_cast<const float2*>(p);
}
__device__ inline float2 load2(const half_t* p) {
    __half2 h = *reinterpret_cast<const __half2*>(p);
    return __half22float2(h);
}
__device__ inline void store_half2(half_t* p, float x, float y) {
    __half2 h = __floats2half2_rn(x, y);
    *reinterpret_cast<__half2*>(p) = h;
}

// ---------------- setup kernels ----------------

__global__ void cnt_hist(const int* __restrict__ col, unsigned* __restrict__ cnt, int E) {
    int e = blockIdx.x * blockDim.x + threadIdx.x;
    if (e < E) atomicAdd(&cnt[col[e]], 1u);
}

__global__ void scan_phase1(const unsigned* __restrict__ cnt, unsigned* __restrict__ bsum, int n) {
    __shared__ unsigned sh[256];
    int t = threadIdx.x;
    int base = blockIdx.x * 1024 + t * 4;
    unsigned s = 0;
#pragma unroll
    for (int j = 0; j < 4; j++) { int i = base + j; if (i < n) s += cnt[i]; }
    sh[t] = s; __syncthreads();
    for (int d = 128; d > 0; d >>= 1) {
        if (t < d) sh[t] += sh[t + d];
        __syncthreads();
    }
    if (t == 0) bsum[blockIdx.x] = sh[0];
}

__global__ void scan_phase2(const unsigned* __restrict__ bsum, unsigned* __restrict__ bbase, int nb) {
    __shared__ unsigned sh[128];
    int t = threadIdx.x;
    unsigned v = (t < nb) ? bsum[t] : 0u;
    sh[t] = v; __syncthreads();
    for (int d = 1; d < 128; d <<= 1) {
        unsigned u = (t >= d) ? sh[t - d] : 0u;
        __syncthreads();
        sh[t] += u;
        __syncthreads();
    }
    if (t < nb) bbase[t] = sh[t] - v;   // exclusive
}

__global__ void scan_phase3(const unsigned* __restrict__ cnt, const unsigned* __restrict__ bbase,
                            unsigned* __restrict__ offsets, int n) {
    __shared__ unsigned sh[256];
    int t = threadIdx.x;
    int base = blockIdx.x * 1024 + t * 4;
    unsigned c[4]; unsigned s = 0;
#pragma unroll
    for (int j = 0; j < 4; j++) { int i = base + j; c[j] = (i < n) ? cnt[i] : 0u; s += c[j]; }
    sh[t] = s; __syncthreads();
    for (int d = 1; d < 256; d <<= 1) {
        unsigned u = (t >= d) ? sh[t - d] : 0u;
        __syncthreads();
        sh[t] += u;
        __syncthreads();
    }
    unsigned o = bbase[blockIdx.x] + sh[t] - s;
#pragma unroll
    for (int j = 0; j < 4; j++) {
        int i = base + j;
        if (i < n) { offsets[i] = o; o += c[j]; }
    }
}

__global__ void csr_build(const int* __restrict__ row, const int* __restrict__ col,
                          const float* __restrict__ w, const unsigned* __restrict__ offsets,
                          unsigned* __restrict__ cursor, int2* __restrict__ ent, int E) {
    int e = blockIdx.x * blockDim.x + threadIdx.x;
    if (e < E) {
        int c = col[e];
        unsigned p = offsets[c] + atomicAdd(&cursor[c], 1u);
        ent[p] = make_int2(row[e], __float_as_int(w[e]));
    }
}

// deg[i] = sum of w over CSR segment i (sequential, no atomics); dinv = rsqrt
__global__ void deg_dinv(const int2* __restrict__ ent, const unsigned* __restrict__ offs,
                         const unsigned* __restrict__ cnt, float* __restrict__ dinv, int n) {
    int i = blockIdx.x * blockDim.x + threadIdx.x;
    if (i < n) {
        unsigned o = offs[i], c = cnt[i];
        float s = 0.f;
        for (unsigned k = 0; k < c; ++k) s += __int_as_float(ent[o + k].y);
        dinv[i] = s > 0.f ? rsqrtf(s) : 0.f;
    }
}

// ent.y = dinv[row] * w   (dst-side dinv applied in spmm epilogue)
__global__ void norm_scale(int2* __restrict__ ent, const float* __restrict__ dinv, int E) {
    int e = blockIdx.x * blockDim.x + threadIdx.x;
    if (e < E) {
        int2 v = ent[e];
        v.y = __float_as_int(dinv[v.x] * __int_as_float(v.y));
        ent[e] = v;
    }
}

// ---------------- dense: C = A @ W (k=0 hop) ----------------

__device__ inline float4 load4(const float* p) {
    return *reinterpret_cast<const float4*>(p);
}
__device__ inline float4 load4(const half_t* p) {
    uint2 u = *reinterpret_cast<const uint2*>(p);
    __half2 a = *reinterpret_cast<__half2*>(&u.x);
    __half2 b = *reinterpret_cast<__half2*>(&u.y);
    float2 fa = __half22float2(a), fb = __half22float2(b);
    return make_float4(fa.x, fa.y, fb.x, fb.y);
}

template <int IN, typename AT>
__global__ __launch_bounds__(256) void matmul_kernel(const AT* __restrict__ A, const float* __restrict__ W,
                                                     float* __restrict__ C, int n) {
    constexpr int AT_S = IN + 12;
    __shared__ float Wl[IN * 64];
    __shared__ float At[64 * AT_S];
    int t = threadIdx.x;
    int nodeBase = blockIdx.x * 64;

#pragma unroll
    for (int idx = t * 4; idx < IN * 64; idx += 1024)
        *reinterpret_cast<float4*>(&Wl[idx]) = *reinterpret_cast<const float4*>(&W[idx]);

#pragma unroll
    for (int idx = t * 4; idx < 64 * IN; idx += 1024) {
        int nd = idx / IN, i = idx % IN;
        float4 v = {0.f, 0.f, 0.f, 0.f};
        if (nodeBase + nd < n) v = load4(A + (size_t)(nodeBase + nd) * IN + i);
        *reinterpret_cast<float4*>(&At[nd * AT_S + i]) = v;
    }
    __syncthreads();

    int tx = t % 16;
    int ty = t / 16;
    float4 acc[4] = {};
    for (int i4 = 0; i4 < IN; i4 += 4) {
        float4 av[4];
#pragma unroll
        for (int nn = 0; nn < 4; ++nn)
            av[nn] = *reinterpret_cast<const float4*>(&At[(ty * 4 + nn) * AT_S + i4]);
#pragma unroll
        for (int j = 0; j < 4; ++j) {
            float4 wv = *reinterpret_cast<const float4*>(&Wl[(i4 + j) * 64 + tx * 4]);
#pragma unroll
            for (int nn = 0; nn < 4; ++nn) {
                float a = reinterpret_cast<const float*>(&av[nn])[j];
                acc[nn].x += a * wv.x; acc[nn].y += a * wv.y;
                acc[nn].z += a * wv.z; acc[nn].w += a * wv.w;
            }
        }
    }
#pragma unroll
    for (int nn = 0; nn < 4; ++nn) {
        int node = nodeBase + ty * 4 + nn;
        if (node >= n) continue;
        *reinterpret_cast<float4*>(&C[(size_t)node * 64 + tx * 4]) = acc[nn];
    }
}

// ---------------- fused SpMM + hop-matmul, wave-per-node ----------------
// p[node] = dinv[node] * sum_e w_e * src[row_e]   (DIM wide)
// One wave per node. Lanes: parity group par = l / (DIM/2) processes edges
// e = par, par+NPAR, ...; lane covers dims [2d, 2d+1] via half2/float2.
// Cross-parity combine via shfl_xor. Epilogue: thread = (node, col).
// MODE 0: pout(f16) = p; acc += p @ W
// MODE 1: h(f16)   = relu(acc + p @ W + bias)
// MODE 2: out(f32) = relu(acc + p @ W + bias)

template <int DIM, typename SrcT, int MODE>
__global__ __launch_bounds__(256) void spmm_mm_v2(
    const SrcT* __restrict__ src, half_t* __restrict__ pout,
    const int2* __restrict__ ent, const unsigned* __restrict__ offs,
    const unsigned* __restrict__ cnt, const float* __restrict__ dinv,
    const float* __restrict__ W, float* __restrict__ acc,
    const float* __restrict__ bias, half_t* __restrict__ hdst,
    float* __restrict__ fdst, int n)
{
    constexpr int LPN  = DIM / 2;       // lanes holding distinct dim-pairs (32 or 16)
    constexpr int NPAR = 64 / LPN;      // edge parities per wave (2 or 4)
    constexpr int PS   = DIM + 2;       // padded LDS row stride (floats)
    __shared__ float Wl[DIM * 64];
    __shared__ float ps[4 * PS];
    int t = threadIdx.x;

#pragma unroll
    for (int idx = t * 4; idx < DIM * 64; idx += 1024)
        *reinterpret_cast<float4*>(&Wl[idx]) = *reinterpret_cast<const float4*>(&W[idx]);

    const int w   = t >> 6;             // wave id = node slot in block
    const int l   = t & 63;
    const int par = l / LPN;
    const int d   = l % LPN;
    const int node = blockIdx.x * 4 + w;
    const bool valid = node < n;

    float ax = 0.f, ay = 0.f;
    if (valid) {
        unsigned off = offs[node];
        unsigned c   = cnt[node];
#pragma unroll 2
        for (unsigned e = par; e < c; e += NPAR) {
            int2 en = ent[off + e];
            float wgt = __int_as_float(en.y);
            float2 v = load2(src + (size_t)en.x * DIM + 2 * d);
            ax += wgt * v.x;
            ay += wgt * v.y;
        }
    }
    // combine parity groups (lanes with same d)
#pragma unroll
    for (int m = LPN; m < 64; m <<= 1) {
        ax += __shfl_xor(ax, m);
        ay += __shfl_xor(ay, m);
    }
    if (valid) {
        float dv = dinv[node];
        ax *= dv; ay *= dv;
        if (par == 0) {
            if (MODE == 0) store_half2(pout + (size_t)node * DIM + 2 * d, ax, ay);
            *reinterpret_cast<float2*>(&ps[w * PS + 2 * d]) = make_float2(ax, ay);
        }
    }
    __syncthreads();

    // epilogue: this thread owns (node = blockIdx*4 + w, col = l)
    if (valid) {
        float m_ = 0.f;
#pragma unroll
        for (int i = 0; i < DIM; ++i)
            m_ += ps[w * PS + i] * Wl[i * 64 + l];
        size_t o = (size_t)node * 64 + l;
        if (MODE == 0) {
            acc[o] += m_;
        } else {
            float r = fmaxf(acc[o] + m_ + bias[l], 0.f);
            if (MODE == 1) hdst[o] = __float2half_rn(r);
            else           fdst[o] = r;
        }
    }
}

// ---------------- host ----------------

extern "C" void kernel_launch(void* const* d_in, const int* in_sizes, int n_in,
                              void* d_out, int out_size, void* d_ws, size_t ws_size,
                              hipStream_t stream) {
    const float* x  = (const float*)d_in[0];
    const int*   ei = (const int*)d_in[1];
    const float* ew = (const float*)d_in[2];
    const float* W0 = (const float*)d_in[3];
    const float* b0 = (const float*)d_in[4];
    const float* Ws = (const float*)d_in[5];
    const float* bs = (const float*)d_in[6];
    float* out = (float*)d_out;

    const int* row = ei;
    const int* col = ei + NE;

    char* wsp = (char*)d_ws;
    auto alloc = [&](size_t bytes) -> char* {
        char* p = wsp;
        wsp += (bytes + 255) & ~(size_t)255;
        return p;
    };
    float*    dinv    = (float*)alloc(NN * 4);
    unsigned* cnt     = (unsigned*)alloc(NN * 4);
    unsigned* cursor  = (unsigned*)alloc(NN * 4);
    unsigned* offsets = (unsigned*)alloc(NN * 4);
    unsigned* bsum    = (unsigned*)alloc(256 * 4);
    unsigned* bbase   = (unsigned*)alloc(256 * 4);
    int2*     ent     = (int2*)alloc((size_t)NE * 8);
    half_t*   B0      = (half_t*)alloc((size_t)NN * 64 * 2);  // h (layer input)
    half_t*   B1      = (half_t*)alloc((size_t)NN * 64 * 2);  // hop ping
    half_t*   B2      = (half_t*)alloc((size_t)NN * 64 * 2);  // hop pong

    hipMemsetAsync(cnt, 0, NN * 4, stream);
    hipMemsetAsync(cursor, 0, NN * 4, stream);

    const int EB = (NE + 255) / 256;         // 6250
    const int NB = (NN + 1023) / 1024;       // 98
    cnt_hist<<<EB, 256, 0, stream>>>(col, cnt, NE);
    scan_phase1<<<NB, 256, 0, stream>>>(cnt, bsum, NN);
    scan_phase2<<<1, 128, 0, stream>>>(bsum, bbase, NB);
    scan_phase3<<<NB, 256, 0, stream>>>(cnt, bbase, offsets, NN);
    csr_build<<<EB, 256, 0, stream>>>(row, col, ew, offsets, cursor, ent, NE);
    deg_dinv<<<(NN + 255) / 256, 256, 0, stream>>>(ent, offsets, cnt, dinv, NN);
    norm_scale<<<EB, 256, 0, stream>>>(ent, dinv, NE);

    const int MMB = (NN + 63) / 64;          // 1563
    const int SB  = (NN + 3) / 4;            // 25000 (wave per node, 4 waves/block)

    // ---- layer 0 (gather dim 32) ----
    matmul_kernel<32, float><<<MMB, 256, 0, stream>>>(x, W0, out, NN);
    spmm_mm_v2<32, float, 0><<<SB, 256, 0, stream>>>(
        x, B1, ent, offsets, cnt, dinv, W0 + 2048, out, nullptr, nullptr, nullptr, NN);
    spmm_mm_v2<32, half_t, 0><<<SB, 256, 0, stream>>>(
        B1, B2, ent, offsets, cnt, dinv, W0 + 4096, out, nullptr, nullptr, nullptr, NN);
    spmm_mm_v2<32, half_t, 1><<<SB, 256, 0, stream>>>(
        B2, nullptr, ent, offsets, cnt, dinv, W0 + 6144, out, b0, B0, nullptr, NN);

    // ---- layers 1..4 (gather dim 64) ----
    for (int l = 0; l < 4; ++l) {
        const float* Wl = Ws + (size_t)l * 4 * 64 * 64;
        const float* bl = bs + (size_t)l * 64;
        matmul_kernel<64, half_t><<<MMB, 256, 0, stream>>>(B0, Wl, out, NN);
        spmm_mm_v2<64, half_t, 0><<<SB, 256, 0, stream>>>(
            B0, B1, ent, offsets, cnt, dinv, Wl + 4096, out, nullptr, nullptr, nullptr, NN);
        spmm_mm_v2<64, half_t, 0><<<SB, 256, 0, stream>>>(
            B1, B2, ent, offsets, cnt, dinv, Wl + 8192, out, nullptr, nullptr, nullptr, NN);
        if (l < 3)
            spmm_mm_v2<64, half_t, 1><<<SB, 256, 0, stream>>>(
                B2, nullptr, ent, offsets, cnt, dinv, Wl + 12288, out, bl, B0, nullptr, NN);
        else
            spmm_mm_v2<64, half_t, 2><<<SB, 256, 0, stream>>>(
                B2, nullptr, ent, offsets, cnt, dinv, Wl + 12288, out, bl, nullptr, out, NN);
    }
}

// Round 5
// 973.839 us; speedup vs baseline: 1.7394x; 1.7394x over previous
//
#include <hip/hip_runtime.h>
#include <hip/hip_fp16.h>

#define NN 100000
#define NE 1600000

typedef __half half_t;

// ---------------- helpers ----------------

__device__ inline float4 load4(const float* p) {
    return *reinterpret_cast<const float4*>(p);
}
__device__ inline float4 load4(const half_t* p) {
    uint2 u = *reinterpret_cast<const uint2*>(p);
    __half2 a = *reinterpret_cast<__half2*>(&u.x);
    __half2 b = *reinterpret_cast<__half2*>(&u.y);
    float2 fa = __half22float2(a), fb = __half22float2(b);
    return make_float4(fa.x, fa.y, fb.x, fb.y);
}
__device__ inline void store_half4(half_t* p, float4 v) {
    __half2 a = __floats2half2_rn(v.x, v.y);
    __half2 b = __floats2half2_rn(v.z, v.w);
    uint2 u;
    u.x = *reinterpret_cast<unsigned*>(&a);
    u.y = *reinterpret_cast<unsigned*>(&b);
    *reinterpret_cast<uint2*>(p) = u;
}

// ---------------- setup kernels ----------------

__global__ void cnt_hist(const int* __restrict__ col, unsigned* __restrict__ cnt, int E) {
    int e = blockIdx.x * blockDim.x + threadIdx.x;
    if (e < E) atomicAdd(&cnt[col[e]], 1u);
}

__global__ void scan_phase1(const unsigned* __restrict__ cnt, unsigned* __restrict__ bsum, int n) {
    __shared__ unsigned sh[256];
    int t = threadIdx.x;
    int base = blockIdx.x * 1024 + t * 4;
    unsigned s = 0;
#pragma unroll
    for (int j = 0; j < 4; j++) { int i = base + j; if (i < n) s += cnt[i]; }
    sh[t] = s; __syncthreads();
    for (int d = 128; d > 0; d >>= 1) {
        if (t < d) sh[t] += sh[t + d];
        __syncthreads();
    }
    if (t == 0) bsum[blockIdx.x] = sh[0];
}

__global__ void scan_phase2(const unsigned* __restrict__ bsum, unsigned* __restrict__ bbase, int nb) {
    __shared__ unsigned sh[128];
    int t = threadIdx.x;
    unsigned v = (t < nb) ? bsum[t] : 0u;
    sh[t] = v; __syncthreads();
    for (int d = 1; d < 128; d <<= 1) {
        unsigned u = (t >= d) ? sh[t - d] : 0u;
        __syncthreads();
        sh[t] += u;
        __syncthreads();
    }
    if (t < nb) bbase[t] = sh[t] - v;   // exclusive
}

__global__ void scan_phase3(const unsigned* __restrict__ cnt, const unsigned* __restrict__ bbase,
                            unsigned* __restrict__ offsets, int n) {
    __shared__ unsigned sh[256];
    int t = threadIdx.x;
    int base = blockIdx.x * 1024 + t * 4;
    unsigned c[4]; unsigned s = 0;
#pragma unroll
    for (int j = 0; j < 4; j++) { int i = base + j; c[j] = (i < n) ? cnt[i] : 0u; s += c[j]; }
    sh[t] = s; __syncthreads();
    for (int d = 1; d < 256; d <<= 1) {
        unsigned u = (t >= d) ? sh[t - d] : 0u;
        __syncthreads();
        sh[t] += u;
        __syncthreads();
    }
    unsigned o = bbase[blockIdx.x] + sh[t] - s;
#pragma unroll
    for (int j = 0; j < 4; j++) {
        int i = base + j;
        if (i < n) { offsets[i] = o; o += c[j]; }
    }
}

__global__ void csr_build(const int* __restrict__ row, const int* __restrict__ col,
                          const float* __restrict__ w, const unsigned* __restrict__ offsets,
                          unsigned* __restrict__ cursor, int2* __restrict__ ent, int E) {
    int e = blockIdx.x * blockDim.x + threadIdx.x;
    if (e < E) {
        int c = col[e];
        unsigned p = offsets[c] + atomicAdd(&cursor[c], 1u);
        ent[p] = make_int2(row[e], __float_as_int(w[e]));
    }
}

// deg[i] = sum of w over CSR segment i (sequential, no atomics); dinv = rsqrt
__global__ void deg_dinv(const int2* __restrict__ ent, const unsigned* __restrict__ offs,
                         const unsigned* __restrict__ cnt, float* __restrict__ dinv, int n) {
    int i = blockIdx.x * blockDim.x + threadIdx.x;
    if (i < n) {
        unsigned o = offs[i], c = cnt[i];
        float s = 0.f;
        for (unsigned k = 0; k < c; ++k) s += __int_as_float(ent[o + k].y);
        dinv[i] = s > 0.f ? rsqrtf(s) : 0.f;
    }
}

// ent.y = dinv[row] * w   (dst-side dinv applied in spmm)
__global__ void norm_scale(int2* __restrict__ ent, const float* __restrict__ dinv, int E) {
    int e = blockIdx.x * blockDim.x + threadIdx.x;
    if (e < E) {
        int2 v = ent[e];
        v.y = __float_as_int(dinv[v.x] * __int_as_float(v.y));
        ent[e] = v;
    }
}

// ---------------- pure SpMM: pout(f16) = dinv[.] * sum_e w_e * src[row_e] ----------------
// v1 mapping (proven): TPN = DIM/4 threads per node, 256/TPN nodes per block.

template <int DIM, typename SrcT>
__global__ __launch_bounds__(256) void spmm_kernel(
    const SrcT* __restrict__ src, half_t* __restrict__ pout,
    const int2* __restrict__ ent, const unsigned* __restrict__ offs,
    const unsigned* __restrict__ cnt, const float* __restrict__ dinv, int n)
{
    constexpr int TPN = DIM / 4;
    constexpr int NPB = 256 / TPN;
    int node = blockIdx.x * NPB + threadIdx.x / TPN;
    int f = (threadIdx.x % TPN) * 4;
    if (node >= n) return;
    unsigned off = offs[node];
    unsigned c = cnt[node];
    float dv = dinv[node];
    float4 a = {0.f, 0.f, 0.f, 0.f};
#pragma unroll 2
    for (unsigned e = off; e < off + c; ++e) {
        int2 en = ent[e];
        float w = __int_as_float(en.y);
        float4 v = load4(src + (size_t)en.x * DIM + f);
        a.x += w * v.x; a.y += w * v.y; a.z += w * v.z; a.w += w * v.w;
    }
    a.x *= dv; a.y *= dv; a.z *= dv; a.w *= dv;
    store_half4(pout + (size_t)node * DIM + f, a);
}

// ---------------- fused 4-source matmul ----------------
// dst = relu( A0@W[0] + P1@W[1] + P2@W[2] + P3@W[3] + bias )
// W: (4, IN, 64). MODE 1: f16 -> hdst. MODE 2: f32 -> fdst.
// Each block owns 64 nodes; reads only its own rows, so hdst==A0 is safe.

template <int IN, typename A0T, int MODE>
__global__ __launch_bounds__(256) void fused4_kernel(
    const A0T* __restrict__ A0, const half_t* __restrict__ P1,
    const half_t* __restrict__ P2, const half_t* __restrict__ P3,
    const float* __restrict__ W, const float* __restrict__ bias,
    half_t* __restrict__ hdst, float* __restrict__ fdst, int n)
{
    constexpr int AT_S = IN + 4;
    __shared__ float Wl[IN * 64];
    __shared__ float At[64 * AT_S];
    int t = threadIdx.x;
    int nodeBase = blockIdx.x * 64;
    int tx = t % 16;   // col quad: cols tx*4..tx*4+3
    int ty = t / 16;   // node quad: nodes ty*4..ty*4+3
    float4 acc[4] = {};

    for (int s = 0; s < 4; ++s) {
        const float* Wsrc = W + s * IN * 64;
#pragma unroll
        for (int idx = t * 4; idx < IN * 64; idx += 1024)
            *reinterpret_cast<float4*>(&Wl[idx]) = *reinterpret_cast<const float4*>(&Wsrc[idx]);
#pragma unroll
        for (int idx = t * 4; idx < 64 * IN; idx += 1024) {
            int nd = idx / IN, i = idx % IN;
            float4 v = {0.f, 0.f, 0.f, 0.f};
            if (nodeBase + nd < n) {
                size_t o = (size_t)(nodeBase + nd) * IN + i;
                if (s == 0)      v = load4(A0 + o);
                else if (s == 1) v = load4(P1 + o);
                else if (s == 2) v = load4(P2 + o);
                else             v = load4(P3 + o);
            }
            *reinterpret_cast<float4*>(&At[nd * AT_S + i]) = v;
        }
        __syncthreads();

        for (int i4 = 0; i4 < IN; i4 += 4) {
            float4 av[4];
#pragma unroll
            for (int nn = 0; nn < 4; ++nn)
                av[nn] = *reinterpret_cast<const float4*>(&At[(ty * 4 + nn) * AT_S + i4]);
#pragma unroll
            for (int j = 0; j < 4; ++j) {
                float4 wv = *reinterpret_cast<const float4*>(&Wl[(i4 + j) * 64 + tx * 4]);
#pragma unroll
                for (int nn = 0; nn < 4; ++nn) {
                    float a = reinterpret_cast<const float*>(&av[nn])[j];
                    acc[nn].x += a * wv.x; acc[nn].y += a * wv.y;
                    acc[nn].z += a * wv.z; acc[nn].w += a * wv.w;
                }
            }
        }
        __syncthreads();   // protect LDS before next source overwrites
    }

    float4 bv = *reinterpret_cast<const float4*>(&bias[tx * 4]);
#pragma unroll
    for (int nn = 0; nn < 4; ++nn) {
        int node = nodeBase + ty * 4 + nn;
        if (node >= n) continue;
        size_t o = (size_t)node * 64 + tx * 4;
        float4 r = acc[nn];
        r.x = fmaxf(r.x + bv.x, 0.f);
        r.y = fmaxf(r.y + bv.y, 0.f);
        r.z = fmaxf(r.z + bv.z, 0.f);
        r.w = fmaxf(r.w + bv.w, 0.f);
        if (MODE == 1) store_half4(hdst + o, r);
        else           *reinterpret_cast<float4*>(&fdst[o]) = r;
    }
}

// ---------------- host ----------------

extern "C" void kernel_launch(void* const* d_in, const int* in_sizes, int n_in,
                              void* d_out, int out_size, void* d_ws, size_t ws_size,
                              hipStream_t stream) {
    const float* x  = (const float*)d_in[0];
    const int*   ei = (const int*)d_in[1];
    const float* ew = (const float*)d_in[2];
    const float* W0 = (const float*)d_in[3];
    const float* b0 = (const float*)d_in[4];
    const float* Ws = (const float*)d_in[5];
    const float* bs = (const float*)d_in[6];
    float* out = (float*)d_out;

    const int* row = ei;
    const int* col = ei + NE;

    char* wsp = (char*)d_ws;
    auto alloc = [&](size_t bytes) -> char* {
        char* p = wsp;
        wsp += (bytes + 255) & ~(size_t)255;
        return p;
    };
    float*    dinv    = (float*)alloc(NN * 4);
    unsigned* cnt     = (unsigned*)alloc(NN * 4);
    unsigned* cursor  = (unsigned*)alloc(NN * 4);
    unsigned* offsets = (unsigned*)alloc(NN * 4);
    unsigned* bsum    = (unsigned*)alloc(256 * 4);
    unsigned* bbase   = (unsigned*)alloc(256 * 4);
    int2*     ent     = (int2*)alloc((size_t)NE * 8);
    half_t*   B0      = (half_t*)alloc((size_t)NN * 64 * 2);  // h (layer input)
    half_t*   P1      = (half_t*)alloc((size_t)NN * 64 * 2);
    half_t*   P2      = (half_t*)alloc((size_t)NN * 64 * 2);
    half_t*   P3      = (half_t*)alloc((size_t)NN * 64 * 2);

    hipMemsetAsync(cnt, 0, NN * 4, stream);
    hipMemsetAsync(cursor, 0, NN * 4, stream);

    const int EB = (NE + 255) / 256;         // 6250
    const int NB = (NN + 1023) / 1024;       // 98
    cnt_hist<<<EB, 256, 0, stream>>>(col, cnt, NE);
    scan_phase1<<<NB, 256, 0, stream>>>(cnt, bsum, NN);
    scan_phase2<<<1, 128, 0, stream>>>(bsum, bbase, NB);
    scan_phase3<<<NB, 256, 0, stream>>>(cnt, bbase, offsets, NN);
    csr_build<<<EB, 256, 0, stream>>>(row, col, ew, offsets, cursor, ent, NE);
    deg_dinv<<<(NN + 255) / 256, 256, 0, stream>>>(ent, offsets, cnt, dinv, NN);
    norm_scale<<<EB, 256, 0, stream>>>(ent, dinv, NE);

    const int MMB  = (NN + 63) / 64;         // 1563
    const int SB32 = (NN + 31) / 32;         // 3125 (8 threads/node)
    const int SB64 = (NN + 15) / 16;         // 6250 (16 threads/node)

    // ---- layer 0 (dim 32) ----
    spmm_kernel<32, float><<<SB32, 256, 0, stream>>>(x, P1, ent, offsets, cnt, dinv, NN);
    spmm_kernel<32, half_t><<<SB32, 256, 0, stream>>>(P1, P2, ent, offsets, cnt, dinv, NN);
    spmm_kernel<32, half_t><<<SB32, 256, 0, stream>>>(P2, P3, ent, offsets, cnt, dinv, NN);
    fused4_kernel<32, float, 1><<<MMB, 256, 0, stream>>>(x, P1, P2, P3, W0, b0, B0, nullptr, NN);

    // ---- layers 1..4 (dim 64) ----
    for (int l = 0; l < 4; ++l) {
        const float* Wl = Ws + (size_t)l * 4 * 64 * 64;
        const float* bl = bs + (size_t)l * 64;
        spmm_kernel<64, half_t><<<SB64, 256, 0, stream>>>(B0, P1, ent, offsets, cnt, dinv, NN);
        spmm_kernel<64, half_t><<<SB64, 256, 0, stream>>>(P1, P2, ent, offsets, cnt, dinv, NN);
        spmm_kernel<64, half_t><<<SB64, 256, 0, stream>>>(P2, P3, ent, offsets, cnt, dinv, NN);
        if (l < 3)
            fused4_kernel<64, half_t, 1><<<MMB, 256, 0, stream>>>(B0, P1, P2, P3, Wl, bl, B0, nullptr, NN);
        else
            fused4_kernel<64, half_t, 2><<<MMB, 256, 0, stream>>>(B0, P1, P2, P3, Wl, bl, nullptr, out, NN);
    }
}

// Round 6
// 798.143 us; speedup vs baseline: 2.1223x; 1.2201x over previous
//
#include <hip/hip_runtime.h>
#include <hip/hip_fp16.h>

#define NN 100000
#define NE 1600000

typedef __half half_t;
using f16x8 = __attribute__((ext_vector_type(8))) _Float16;
using f32x4 = __attribute__((ext_vector_type(4))) float;

// ---------------- helpers ----------------

__device__ inline float4 load4(const float* p) {
    return *reinterpret_cast<const float4*>(p);
}
__device__ inline float4 load4(const half_t* p) {
    uint2 u = *reinterpret_cast<const uint2*>(p);
    __half2 a = *reinterpret_cast<__half2*>(&u.x);
    __half2 b = *reinterpret_cast<__half2*>(&u.y);
    float2 fa = __half22float2(a), fb = __half22float2(b);
    return make_float4(fa.x, fa.y, fb.x, fb.y);
}
__device__ inline void store_half4(half_t* p, float4 v) {
    __half2 a = __floats2half2_rn(v.x, v.y);
    __half2 b = __floats2half2_rn(v.z, v.w);
    uint2 u;
    u.x = *reinterpret_cast<unsigned*>(&a);
    u.y = *reinterpret_cast<unsigned*>(&b);
    *reinterpret_cast<uint2*>(p) = u;
}

// ---------------- setup kernels ----------------

__global__ void cnt_hist(const int* __restrict__ col, unsigned* __restrict__ cnt, int E) {
    int e = blockIdx.x * blockDim.x + threadIdx.x;
    if (e < E) atomicAdd(&cnt[col[e]], 1u);
}

__global__ void f32_to_f16(const float* __restrict__ in, half_t* __restrict__ out, int nquad) {
    int i = blockIdx.x * blockDim.x + threadIdx.x;
    if (i < nquad) store_half4(out + i * 4, load4(in + i * 4));
}

__global__ void scan_phase1(const unsigned* __restrict__ cnt, unsigned* __restrict__ bsum, int n) {
    __shared__ unsigned sh[256];
    int t = threadIdx.x;
    int base = blockIdx.x * 1024 + t * 4;
    unsigned s = 0;
#pragma unroll
    for (int j = 0; j < 4; j++) { int i = base + j; if (i < n) s += cnt[i]; }
    sh[t] = s; __syncthreads();
    for (int d = 128; d > 0; d >>= 1) {
        if (t < d) sh[t] += sh[t + d];
        __syncthreads();
    }
    if (t == 0) bsum[blockIdx.x] = sh[0];
}

__global__ void scan_phase2(const unsigned* __restrict__ bsum, unsigned* __restrict__ bbase, int nb) {
    __shared__ unsigned sh[128];
    int t = threadIdx.x;
    unsigned v = (t < nb) ? bsum[t] : 0u;
    sh[t] = v; __syncthreads();
    for (int d = 1; d < 128; d <<= 1) {
        unsigned u = (t >= d) ? sh[t - d] : 0u;
        __syncthreads();
        sh[t] += u;
        __syncthreads();
    }
    if (t < nb) bbase[t] = sh[t] - v;   // exclusive
}

__global__ void scan_phase3(const unsigned* __restrict__ cnt, const unsigned* __restrict__ bbase,
                            unsigned* __restrict__ offsets, int n) {
    __shared__ unsigned sh[256];
    int t = threadIdx.x;
    int base = blockIdx.x * 1024 + t * 4;
    unsigned c[4]; unsigned s = 0;
#pragma unroll
    for (int j = 0; j < 4; j++) { int i = base + j; c[j] = (i < n) ? cnt[i] : 0u; s += c[j]; }
    sh[t] = s; __syncthreads();
    for (int d = 1; d < 256; d <<= 1) {
        unsigned u = (t >= d) ? sh[t - d] : 0u;
        __syncthreads();
        sh[t] += u;
        __syncthreads();
    }
    unsigned o = bbase[blockIdx.x] + sh[t] - s;
#pragma unroll
    for (int j = 0; j < 4; j++) {
        int i = base + j;
        if (i < n) { offsets[i] = o; o += c[j]; }
    }
}

__global__ void csr_build(const int* __restrict__ row, const int* __restrict__ col,
                          const float* __restrict__ w, const unsigned* __restrict__ offsets,
                          unsigned* __restrict__ cursor, int2* __restrict__ ent, int E) {
    int e = blockIdx.x * blockDim.x + threadIdx.x;
    if (e < E) {
        int c = col[e];
        unsigned p = offsets[c] + atomicAdd(&cursor[c], 1u);
        ent[p] = make_int2(row[e], __float_as_int(w[e]));
    }
}

// deg[i] = sum of w over CSR segment i (sequential, no atomics); dinv = rsqrt
__global__ void deg_dinv(const int2* __restrict__ ent, const unsigned* __restrict__ offs,
                         const unsigned* __restrict__ cnt, float* __restrict__ dinv, int n) {
    int i = blockIdx.x * blockDim.x + threadIdx.x;
    if (i < n) {
        unsigned o = offs[i], c = cnt[i];
        float s = 0.f;
        for (unsigned k = 0; k < c; ++k) s += __int_as_float(ent[o + k].y);
        dinv[i] = s > 0.f ? rsqrtf(s) : 0.f;
    }
}

// ent.y = dinv[row] * w   (dst-side dinv applied in spmm)
__global__ void norm_scale(int2* __restrict__ ent, const float* __restrict__ dinv, int E) {
    int e = blockIdx.x * blockDim.x + threadIdx.x;
    if (e < E) {
        int2 v = ent[e];
        v.y = __float_as_int(dinv[v.x] * __int_as_float(v.y));
        ent[e] = v;
    }
}

// ---------------- pure SpMM dim-32 (v1 mapping, proven) ----------------

template <int DIM, typename SrcT>
__global__ __launch_bounds__(256) void spmm_kernel(
    const SrcT* __restrict__ src, half_t* __restrict__ pout,
    const int2* __restrict__ ent, const unsigned* __restrict__ offs,
    const unsigned* __restrict__ cnt, const float* __restrict__ dinv, int n)
{
    constexpr int TPN = DIM / 4;
    constexpr int NPB = 256 / TPN;
    int node = blockIdx.x * NPB + threadIdx.x / TPN;
    int f = (threadIdx.x % TPN) * 4;
    if (node >= n) return;
    unsigned off = offs[node];
    unsigned c = cnt[node];
    float dv = dinv[node];
    float4 a = {0.f, 0.f, 0.f, 0.f};
#pragma unroll 2
    for (unsigned e = off; e < off + c; ++e) {
        int2 en = ent[e];
        float w = __int_as_float(en.y);
        float4 v = load4(src + (size_t)en.x * DIM + f);
        a.x += w * v.x; a.y += w * v.y; a.z += w * v.z; a.w += w * v.w;
    }
    a.x *= dv; a.y *= dv; a.z *= dv; a.w *= dv;
    store_half4(pout + (size_t)node * DIM + f, a);
}

// ---------------- pure SpMM dim-64, 8 lanes/node, 16B loads ----------------

__global__ __launch_bounds__(256) void spmm64_kernel(
    const half_t* __restrict__ src, half_t* __restrict__ pout,
    const int2* __restrict__ ent, const unsigned* __restrict__ offs,
    const unsigned* __restrict__ cnt, const float* __restrict__ dinv, int n)
{
    int node = blockIdx.x * 32 + (threadIdx.x >> 3);
    int f = (threadIdx.x & 7) * 8;   // 8 halfs = 16B per lane
    if (node >= n) return;
    unsigned off = offs[node], c = cnt[node];
    float dv = dinv[node];
    float acc[8] = {};
#pragma unroll 2
    for (unsigned e = off; e < off + c; ++e) {
        int2 en = ent[e];
        float w = __int_as_float(en.y);
        uint4 raw = *reinterpret_cast<const uint4*>(src + (size_t)en.x * 64 + f);
        __half2* h2 = reinterpret_cast<__half2*>(&raw);
#pragma unroll
        for (int j = 0; j < 4; ++j) {
            float2 v = __half22float2(h2[j]);
            acc[2 * j]     += w * v.x;
            acc[2 * j + 1] += w * v.y;
        }
    }
    uint4 o;
    __half2 h;
    h = __floats2half2_rn(acc[0] * dv, acc[1] * dv); o.x = *reinterpret_cast<unsigned*>(&h);
    h = __floats2half2_rn(acc[2] * dv, acc[3] * dv); o.y = *reinterpret_cast<unsigned*>(&h);
    h = __floats2half2_rn(acc[4] * dv, acc[5] * dv); o.z = *reinterpret_cast<unsigned*>(&h);
    h = __floats2half2_rn(acc[6] * dv, acc[7] * dv); o.w = *reinterpret_cast<unsigned*>(&h);
    *reinterpret_cast<uint4*>(pout + (size_t)node * 64 + f) = o;
}

// ---------------- fused 4-source matmul via MFMA f16 ----------------
// dst = relu( A0@W[0] + P1@W[1] + P2@W[2] + P3@W[3] + bias )
// W: (4, IN, 64) f32, converted to f16 LDS tile Wt[col][k] per source.
// Block: 64 nodes, 4 waves x 16 rows. Wave: 4 col-tiles (16x16), K=IN per source.
// A-frag: lane = row (l&15), 8 contiguous f16 at k=(l>>4)*8 (+32 per kk step).
// C/D: col = l&15, row = (l>>4)*4 + reg  [m89-verified layout].

template <int IN, int MODE>
__global__ __launch_bounds__(256) void fused4_mfma(
    const half_t* __restrict__ A0, const half_t* __restrict__ P1,
    const half_t* __restrict__ P2, const half_t* __restrict__ P3,
    const float* __restrict__ W, const float* __restrict__ bias,
    half_t* __restrict__ hdst, float* __restrict__ fdst, int n)
{
    constexpr int KK  = IN / 32;      // MFMA K-steps per source
    constexpr int WTS = IN + 8;       // padded k-stride (halfs) -> ~2-way banks
    __shared__ _Float16 Wt[64][WTS];
    int t = threadIdx.x;
    int w = t >> 6, l = t & 63;
    int nodeBase = blockIdx.x * 64;
    int rowTop = nodeBase + w * 16;

    f32x4 acc[4];
#pragma unroll
    for (int ct = 0; ct < 4; ++ct) acc[ct] = (f32x4){0.f, 0.f, 0.f, 0.f};

    int row = rowTop + (l & 15);
    if (row >= n) row = n - 1;        // clamp: safe read, stores guarded
    const int khome = (l >> 4) * 8;

#pragma unroll
    for (int s = 0; s < 4; ++s) {
        const half_t* S = (s == 0) ? A0 : (s == 1) ? P1 : (s == 2) ? P2 : P3;
        const float* Wsrc = W + s * IN * 64;
        for (int idx = t; idx < IN * 64; idx += 256) {
            int k = idx >> 6, colj = idx & 63;
            Wt[colj][k] = (_Float16)Wsrc[idx];
        }
        __syncthreads();
#pragma unroll
        for (int kk = 0; kk < KK; ++kk) {
            uint4 araw = *reinterpret_cast<const uint4*>(S + (size_t)row * IN + kk * 32 + khome);
            f16x8 afrag = __builtin_bit_cast(f16x8, araw);
#pragma unroll
            for (int ct = 0; ct < 4; ++ct) {
                f16x8 bfrag = *reinterpret_cast<const f16x8*>(&Wt[ct * 16 + (l & 15)][kk * 32 + khome]);
                acc[ct] = __builtin_amdgcn_mfma_f32_16x16x32_f16(afrag, bfrag, acc[ct], 0, 0, 0);
            }
        }
        __syncthreads();   // all reads of S done before next W staging / stores
    }

    int colb = l & 15;
    int rbase = rowTop + (l >> 4) * 4;
#pragma unroll
    for (int ct = 0; ct < 4; ++ct) {
#pragma unroll
        for (int r = 0; r < 4; ++r) {
            int node = rbase + r;
            if (node >= n) continue;
            int colj = ct * 16 + colb;
            float v = fmaxf(acc[ct][r] + bias[colj], 0.f);
            size_t o = (size_t)node * 64 + colj;
            if (MODE == 1) hdst[o] = __float2half_rn(v);
            else           fdst[o] = v;
        }
    }
}

// ---------------- host ----------------

extern "C" void kernel_launch(void* const* d_in, const int* in_sizes, int n_in,
                              void* d_out, int out_size, void* d_ws, size_t ws_size,
                              hipStream_t stream) {
    const float* x  = (const float*)d_in[0];
    const int*   ei = (const int*)d_in[1];
    const float* ew = (const float*)d_in[2];
    const float* W0 = (const float*)d_in[3];
    const float* b0 = (const float*)d_in[4];
    const float* Ws = (const float*)d_in[5];
    const float* bs = (const float*)d_in[6];
    float* out = (float*)d_out;

    const int* row = ei;
    const int* col = ei + NE;

    char* wsp = (char*)d_ws;
    auto alloc = [&](size_t bytes) -> char* {
        char* p = wsp;
        wsp += (bytes + 255) & ~(size_t)255;
        return p;
    };
    float*    dinv    = (float*)alloc(NN * 4);
    unsigned* cnt     = (unsigned*)alloc(NN * 4);
    unsigned* cursor  = (unsigned*)alloc(NN * 4);
    unsigned* offsets = (unsigned*)alloc(NN * 4);
    unsigned* bsum    = (unsigned*)alloc(256 * 4);
    unsigned* bbase   = (unsigned*)alloc(256 * 4);
    int2*     ent     = (int2*)alloc((size_t)NE * 8);
    half_t*   xh      = (half_t*)alloc((size_t)NN * 32 * 2);
    half_t*   B0      = (half_t*)alloc((size_t)NN * 64 * 2);  // h (layer input)
    half_t*   P1      = (half_t*)alloc((size_t)NN * 64 * 2);
    half_t*   P2      = (half_t*)alloc((size_t)NN * 64 * 2);
    half_t*   P3      = (half_t*)alloc((size_t)NN * 64 * 2);

    hipMemsetAsync(cnt, 0, NN * 4, stream);
    hipMemsetAsync(cursor, 0, NN * 4, stream);

    const int EB = (NE + 255) / 256;         // 6250
    const int NB = (NN + 1023) / 1024;       // 98
    cnt_hist<<<EB, 256, 0, stream>>>(col, cnt, NE);
    f32_to_f16<<<(NN * 32 / 4 + 255) / 256, 256, 0, stream>>>(x, xh, NN * 32 / 4);
    scan_phase1<<<NB, 256, 0, stream>>>(cnt, bsum, NN);
    scan_phase2<<<1, 128, 0, stream>>>(bsum, bbase, NB);
    scan_phase3<<<NB, 256, 0, stream>>>(cnt, bbase, offsets, NN);
    csr_build<<<EB, 256, 0, stream>>>(row, col, ew, offsets, cursor, ent, NE);
    deg_dinv<<<(NN + 255) / 256, 256, 0, stream>>>(ent, offsets, cnt, dinv, NN);
    norm_scale<<<EB, 256, 0, stream>>>(ent, dinv, NE);

    const int MMB  = (NN + 63) / 64;         // 1563
    const int SB32 = (NN + 31) / 32;         // 3125 (8 threads/node, dim32)
    const int SB64 = (NN + 31) / 32;         // 3125 (8 threads/node, dim64, 16B lanes)

    // ---- layer 0 (dim 32) ----
    spmm_kernel<32, float><<<SB32, 256, 0, stream>>>(x, P1, ent, offsets, cnt, dinv, NN);
    spmm_kernel<32, half_t><<<SB32, 256, 0, stream>>>(P1, P2, ent, offsets, cnt, dinv, NN);
    spmm_kernel<32, half_t><<<SB32, 256, 0, stream>>>(P2, P3, ent, offsets, cnt, dinv, NN);
    fused4_mfma<32, 1><<<MMB, 256, 0, stream>>>(xh, P1, P2, P3, W0, b0, B0, nullptr, NN);

    // ---- layers 1..4 (dim 64) ----
    for (int l = 0; l < 4; ++l) {
        const float* Wl = Ws + (size_t)l * 4 * 64 * 64;
        const float* bl = bs + (size_t)l * 64;
        spmm64_kernel<<<SB64, 256, 0, stream>>>(B0, P1, ent, offsets, cnt, dinv, NN);
        spmm64_kernel<<<SB64, 256, 0, stream>>>(P1, P2, ent, offsets, cnt, dinv, NN);
        spmm64_kernel<<<SB64, 256, 0, stream>>>(P2, P3, ent, offsets, cnt, dinv, NN);
        if (l < 3)
            fused4_mfma<64, 1><<<MMB, 256, 0, stream>>>(B0, P1, P2, P3, Wl, bl, B0, nullptr, NN);
        else
            fused4_mfma<64, 2><<<MMB, 256, 0, stream>>>(B0, P1, P2, P3, Wl, bl, nullptr, out, NN);
    }
}

// Round 7
// 664.110 us; speedup vs baseline: 2.5507x; 1.2018x over previous
//
#include <hip/hip_runtime.h>
#include <hip/hip_fp16.h>

#define NN 100000
#define NE 1600000
#define NBKT 196              // buckets of 512 cols: 99999>>9 = 195
#define BSH 9
#define BCAP 9216             // mean 8163 + 11.7 sigma
#define NCOL (NBKT * 512)     // 100352 = 98 * 1024 (scan-friendly)
#define EPB_A 4096

typedef __half half_t;
using f16x8 = __attribute__((ext_vector_type(8))) _Float16;
using f32x4 = __attribute__((ext_vector_type(4))) float;

// ---------------- helpers ----------------

__device__ inline float4 load4(const float* p) {
    return *reinterpret_cast<const float4*>(p);
}
__device__ inline float4 load4(const half_t* p) {
    uint2 u = *reinterpret_cast<const uint2*>(p);
    __half2 a = *reinterpret_cast<__half2*>(&u.x);
    __half2 b = *reinterpret_cast<__half2*>(&u.y);
    float2 fa = __half22float2(a), fb = __half22float2(b);
    return make_float4(fa.x, fa.y, fb.x, fb.y);
}
__device__ inline void store_half4(half_t* p, float4 v) {
    __half2 a = __floats2half2_rn(v.x, v.y);
    __half2 b = __floats2half2_rn(v.z, v.w);
    uint2 u;
    u.x = *reinterpret_cast<unsigned*>(&a);
    u.y = *reinterpret_cast<unsigned*>(&b);
    *reinterpret_cast<uint2*>(p) = u;
}

// ---------------- setup: two-level bucket CSR build ----------------

__global__ void f32_to_f16(const float* __restrict__ in, half_t* __restrict__ out, int nquad) {
    int i = blockIdx.x * blockDim.x + threadIdx.x;
    if (i < nquad) store_half4(out + i * 4, load4(in + i * 4));
}

// passA: block-local counting sort by coarse bucket, sequential flush.
// packed = (col&511)<<17 | row   (row < 2^17)
__global__ __launch_bounds__(256) void passA_bucket(
    const int* __restrict__ row, const int* __restrict__ col, const float* __restrict__ w,
    unsigned* __restrict__ gcur, int2* __restrict__ gbkt, int E)
{
    __shared__ unsigned cnt[256];
    __shared__ unsigned lofs[256];
    __shared__ unsigned lcur[256];
    __shared__ unsigned gb[256];
    __shared__ int2 arena[EPB_A];
    __shared__ unsigned short abkt[EPB_A];
    int t = threadIdx.x;
    int base = blockIdx.x * EPB_A;
    int nloc = min(EPB_A, E - base);
    cnt[t] = 0; lcur[t] = 0;
    __syncthreads();
    for (int i = t; i < nloc; i += 256)
        atomicAdd(&cnt[col[base + i] >> BSH], 1u);
    __syncthreads();
    // exclusive scan of cnt -> lofs (Hillis-Steele on 256)
    unsigned v = cnt[t];
    lofs[t] = v; __syncthreads();
    for (int d = 1; d < 256; d <<= 1) {
        unsigned u = (t >= d) ? lofs[t - d] : 0u;
        __syncthreads();
        lofs[t] += u;
        __syncthreads();
    }
    unsigned excl = lofs[t] - v;
    __syncthreads();
    lofs[t] = excl;
    __syncthreads();
    // reserve global space per bucket (few atomics)
    if (t < NBKT && cnt[t] > 0) gb[t] = atomicAdd(&gcur[t], cnt[t]);
    // place into arena (bucket-sorted)
    for (int i = t; i < nloc; i += 256) {
        int e = base + i;
        int c = col[e];
        int b = c >> BSH;
        unsigned p = lofs[b] + atomicAdd(&lcur[b], 1u);
        unsigned packed = ((unsigned)(c & 511) << 17) | (unsigned)row[e];
        arena[p] = make_int2((int)packed, __float_as_int(w[e]));
        abkt[p] = (unsigned short)b;
    }
    __syncthreads();
    // flush: consecutive arena slots -> consecutive global addrs (coalesced)
    for (int i = t; i < nloc; i += 256) {
        int b = abkt[i];
        unsigned j = i - lofs[b];
        gbkt[(size_t)b * BCAP + gb[b] + j] = arena[i];
    }
}

// passB: per-bucket 512-col histogram + weighted degree, sequential writes
__global__ __launch_bounds__(256) void passB_hist(
    const int2* __restrict__ gbkt, const unsigned* __restrict__ gcur,
    unsigned* __restrict__ cnt, float* __restrict__ deg)
{
    __shared__ unsigned c512[512];
    __shared__ float d512[512];
    int t = threadIdx.x;
    int b = blockIdx.x;
    for (int i = t; i < 512; i += 256) { c512[i] = 0; d512[i] = 0.f; }
    __syncthreads();
    unsigned sz = min(gcur[b], (unsigned)BCAP);
    const int2* src = gbkt + (size_t)b * BCAP;
    for (unsigned i = t; i < sz; i += 256) {
        int2 v = src[i];
        unsigned colw = ((unsigned)v.x) >> 17;
        atomicAdd(&c512[colw], 1u);
        atomicAdd(&d512[colw], __int_as_float(v.y));
    }
    __syncthreads();
    for (int i = t; i < 512; i += 256) {
        cnt[b * 512 + i] = c512[i];
        deg[b * 512 + i] = d512[i];
    }
}

__global__ void dinv_kernel(const float* __restrict__ deg, float* __restrict__ dinv, int n) {
    int i = blockIdx.x * blockDim.x + threadIdx.x;
    if (i < n) {
        float d = deg[i];
        dinv[i] = d > 0.f ? rsqrtf(d) : 0.f;
    }
}

__global__ void scan_phase1(const unsigned* __restrict__ cnt, unsigned* __restrict__ bsum, int n) {
    __shared__ unsigned sh[256];
    int t = threadIdx.x;
    int base = blockIdx.x * 1024 + t * 4;
    unsigned s = 0;
#pragma unroll
    for (int j = 0; j < 4; j++) { int i = base + j; if (i < n) s += cnt[i]; }
    sh[t] = s; __syncthreads();
    for (int d = 128; d > 0; d >>= 1) {
        if (t < d) sh[t] += sh[t + d];
        __syncthreads();
    }
    if (t == 0) bsum[blockIdx.x] = sh[0];
}

__global__ void scan_phase2(const unsigned* __restrict__ bsum, unsigned* __restrict__ bbase, int nb) {
    __shared__ unsigned sh[128];
    int t = threadIdx.x;
    unsigned v = (t < nb) ? bsum[t] : 0u;
    sh[t] = v; __syncthreads();
    for (int d = 1; d < 128; d <<= 1) {
        unsigned u = (t >= d) ? sh[t - d] : 0u;
        __syncthreads();
        sh[t] += u;
        __syncthreads();
    }
    if (t < nb) bbase[t] = sh[t] - v;   // exclusive
}

__global__ void scan_phase3(const unsigned* __restrict__ cnt, const unsigned* __restrict__ bbase,
                            unsigned* __restrict__ offsets, int n) {
    __shared__ unsigned sh[256];
    int t = threadIdx.x;
    int base = blockIdx.x * 1024 + t * 4;
    unsigned c[4]; unsigned s = 0;
#pragma unroll
    for (int j = 0; j < 4; j++) { int i = base + j; c[j] = (i < n) ? cnt[i] : 0u; s += c[j]; }
    sh[t] = s; __syncthreads();
    for (int d = 1; d < 256; d <<= 1) {
        unsigned u = (t >= d) ? sh[t - d] : 0u;
        __syncthreads();
        sh[t] += u;
        __syncthreads();
    }
    unsigned o = bbase[blockIdx.x] + sh[t] - s;
#pragma unroll
    for (int j = 0; j < 4; j++) {
        int i = base + j;
        if (i < n) { offsets[i] = o; o += c[j]; }
    }
}

// passC: per-bucket placement into final CSR; scatter window ~65KB (L2-resident).
// ent.y = dinv[row] * w  (dst-side dinv applied in spmm)
__global__ __launch_bounds__(256) void passC_place(
    const int2* __restrict__ gbkt, const unsigned* __restrict__ gcur,
    const unsigned* __restrict__ offsets, const float* __restrict__ dinv,
    int2* __restrict__ ent)
{
    __shared__ unsigned lcur[512];
    int t = threadIdx.x;
    int b = blockIdx.x;
    for (int i = t; i < 512; i += 256) lcur[i] = 0;
    __syncthreads();
    unsigned sz = min(gcur[b], (unsigned)BCAP);
    const int2* src = gbkt + (size_t)b * BCAP;
    for (unsigned i = t; i < sz; i += 256) {
        int2 v = src[i];
        unsigned colw = ((unsigned)v.x) >> 17;
        int r = v.x & 0x1FFFF;
        int c = (b << BSH) | (int)colw;
        unsigned pos = offsets[c] + atomicAdd(&lcur[colw], 1u);
        float wv = __int_as_float(v.y) * dinv[r];
        ent[pos] = make_int2(r, __float_as_int(wv));
    }
}

// ---------------- pure SpMM dim-32 (v1 mapping, proven) ----------------

template <int DIM, typename SrcT>
__global__ __launch_bounds__(256) void spmm_kernel(
    const SrcT* __restrict__ src, half_t* __restrict__ pout,
    const int2* __restrict__ ent, const unsigned* __restrict__ offs,
    const unsigned* __restrict__ cnt, const float* __restrict__ dinv, int n)
{
    constexpr int TPN = DIM / 4;
    constexpr int NPB = 256 / TPN;
    int node = blockIdx.x * NPB + threadIdx.x / TPN;
    int f = (threadIdx.x % TPN) * 4;
    if (node >= n) return;
    unsigned off = offs[node];
    unsigned c = cnt[node];
    float dv = dinv[node];
    float4 a = {0.f, 0.f, 0.f, 0.f};
#pragma unroll 2
    for (unsigned e = off; e < off + c; ++e) {
        int2 en = ent[e];
        float w = __int_as_float(en.y);
        float4 v = load4(src + (size_t)en.x * DIM + f);
        a.x += w * v.x; a.y += w * v.y; a.z += w * v.z; a.w += w * v.w;
    }
    a.x *= dv; a.y *= dv; a.z *= dv; a.w *= dv;
    store_half4(pout + (size_t)node * DIM + f, a);
}

// ---------------- pure SpMM dim-64, 8 lanes/node, 16B loads ----------------

__global__ __launch_bounds__(256) void spmm64_kernel(
    const half_t* __restrict__ src, half_t* __restrict__ pout,
    const int2* __restrict__ ent, const unsigned* __restrict__ offs,
    const unsigned* __restrict__ cnt, const float* __restrict__ dinv, int n)
{
    int node = blockIdx.x * 32 + (threadIdx.x >> 3);
    int f = (threadIdx.x & 7) * 8;   // 8 halfs = 16B per lane
    if (node >= n) return;
    unsigned off = offs[node], c = cnt[node];
    float dv = dinv[node];
    float acc[8] = {};
#pragma unroll 2
    for (unsigned e = off; e < off + c; ++e) {
        int2 en = ent[e];
        float w = __int_as_float(en.y);
        uint4 raw = *reinterpret_cast<const uint4*>(src + (size_t)en.x * 64 + f);
        __half2* h2 = reinterpret_cast<__half2*>(&raw);
#pragma unroll
        for (int j = 0; j < 4; ++j) {
            float2 v = __half22float2(h2[j]);
            acc[2 * j]     += w * v.x;
            acc[2 * j + 1] += w * v.y;
        }
    }
    uint4 o;
    __half2 h;
    h = __floats2half2_rn(acc[0] * dv, acc[1] * dv); o.x = *reinterpret_cast<unsigned*>(&h);
    h = __floats2half2_rn(acc[2] * dv, acc[3] * dv); o.y = *reinterpret_cast<unsigned*>(&h);
    h = __floats2half2_rn(acc[4] * dv, acc[5] * dv); o.z = *reinterpret_cast<unsigned*>(&h);
    h = __floats2half2_rn(acc[6] * dv, acc[7] * dv); o.w = *reinterpret_cast<unsigned*>(&h);
    *reinterpret_cast<uint4*>(pout + (size_t)node * 64 + f) = o;
}

// ---------------- fused 4-source matmul via MFMA f16 ----------------

template <int IN, int MODE>
__global__ __launch_bounds__(256) void fused4_mfma(
    const half_t* __restrict__ A0, const half_t* __restrict__ P1,
    const half_t* __restrict__ P2, const half_t* __restrict__ P3,
    const float* __restrict__ W, const float* __restrict__ bias,
    half_t* __restrict__ hdst, float* __restrict__ fdst, int n)
{
    constexpr int KK  = IN / 32;
    constexpr int WTS = IN + 8;
    __shared__ _Float16 Wt[64][WTS];
    int t = threadIdx.x;
    int w = t >> 6, l = t & 63;
    int nodeBase = blockIdx.x * 64;
    int rowTop = nodeBase + w * 16;

    f32x4 acc[4];
#pragma unroll
    for (int ct = 0; ct < 4; ++ct) acc[ct] = (f32x4){0.f, 0.f, 0.f, 0.f};

    int row = rowTop + (l & 15);
    if (row >= n) row = n - 1;
    const int khome = (l >> 4) * 8;

#pragma unroll
    for (int s = 0; s < 4; ++s) {
        const half_t* S = (s == 0) ? A0 : (s == 1) ? P1 : (s == 2) ? P2 : P3;
        const float* Wsrc = W + s * IN * 64;
        for (int idx = t; idx < IN * 64; idx += 256) {
            int k = idx >> 6, colj = idx & 63;
            Wt[colj][k] = (_Float16)Wsrc[idx];
        }
        __syncthreads();
#pragma unroll
        for (int kk = 0; kk < KK; ++kk) {
            uint4 araw = *reinterpret_cast<const uint4*>(S + (size_t)row * IN + kk * 32 + khome);
            f16x8 afrag = __builtin_bit_cast(f16x8, araw);
#pragma unroll
            for (int ct = 0; ct < 4; ++ct) {
                f16x8 bfrag = *reinterpret_cast<const f16x8*>(&Wt[ct * 16 + (l & 15)][kk * 32 + khome]);
                acc[ct] = __builtin_amdgcn_mfma_f32_16x16x32_f16(afrag, bfrag, acc[ct], 0, 0, 0);
            }
        }
        __syncthreads();
    }

    int colb = l & 15;
    int rbase = rowTop + (l >> 4) * 4;
#pragma unroll
    for (int ct = 0; ct < 4; ++ct) {
#pragma unroll
        for (int r = 0; r < 4; ++r) {
            int node = rbase + r;
            if (node >= n) continue;
            int colj = ct * 16 + colb;
            float v = fmaxf(acc[ct][r] + bias[colj], 0.f);
            size_t o = (size_t)node * 64 + colj;
            if (MODE == 1) hdst[o] = __float2half_rn(v);
            else           fdst[o] = v;
        }
    }
}

// ---------------- host ----------------

extern "C" void kernel_launch(void* const* d_in, const int* in_sizes, int n_in,
                              void* d_out, int out_size, void* d_ws, size_t ws_size,
                              hipStream_t stream) {
    const float* x  = (const float*)d_in[0];
    const int*   ei = (const int*)d_in[1];
    const float* ew = (const float*)d_in[2];
    const float* W0 = (const float*)d_in[3];
    const float* b0 = (const float*)d_in[4];
    const float* Ws = (const float*)d_in[5];
    const float* bs = (const float*)d_in[6];
    float* out = (float*)d_out;

    const int* row = ei;
    const int* col = ei + NE;

    char* wsp = (char*)d_ws;
    auto alloc = [&](size_t bytes) -> char* {
        char* p = wsp;
        wsp += (bytes + 255) & ~(size_t)255;
        return p;
    };
    float*    dinv    = (float*)alloc((size_t)NCOL * 4);
    float*    deg     = (float*)alloc((size_t)NCOL * 4);
    unsigned* cnt     = (unsigned*)alloc((size_t)NCOL * 4);
    unsigned* offsets = (unsigned*)alloc((size_t)NCOL * 4);
    unsigned* bsum    = (unsigned*)alloc(256 * 4);
    unsigned* bbase   = (unsigned*)alloc(256 * 4);
    unsigned* gcur    = (unsigned*)alloc(NBKT * 4);
    int2*     ent     = (int2*)alloc((size_t)NE * 8);
    half_t*   xh      = (half_t*)alloc((size_t)NN * 32 * 2);
    half_t*   B0      = (half_t*)alloc((size_t)NN * 64 * 2);
    half_t*   P1      = (half_t*)alloc((size_t)NN * 64 * 2);
    half_t*   P2      = (half_t*)alloc((size_t)NN * 64 * 2);
    half_t*   P3      = (half_t*)alloc((size_t)NN * 64 * 2);
    // bucket staging aliases P1/P2 (first written after passC in stream order)
    int2*     gbkt    = (int2*)P1;   // needs 196*9216*8 = 14.45 MB < 25.6 MB (P1+P2)

    hipMemsetAsync(gcur, 0, NBKT * 4, stream);

    f32_to_f16<<<(NN * 32 / 4 + 255) / 256, 256, 0, stream>>>(x, xh, NN * 32 / 4);

    const int AB = (NE + EPB_A - 1) / EPB_A;   // 391
    passA_bucket<<<AB, 256, 0, stream>>>(row, col, ew, gcur, gbkt, NE);
    passB_hist<<<NBKT, 256, 0, stream>>>(gbkt, gcur, cnt, deg);
    dinv_kernel<<<(NN + 255) / 256, 256, 0, stream>>>(deg, dinv, NN);
    const int NB = NCOL / 1024;                // 98 exactly
    scan_phase1<<<NB, 256, 0, stream>>>(cnt, bsum, NCOL);
    scan_phase2<<<1, 128, 0, stream>>>(bsum, bbase, NB);
    scan_phase3<<<NB, 256, 0, stream>>>(cnt, bbase, offsets, NCOL);
    passC_place<<<NBKT, 256, 0, stream>>>(gbkt, gcur, offsets, dinv, ent);

    const int MMB  = (NN + 63) / 64;           // 1563
    const int SB32 = (NN + 31) / 32;           // 3125
    const int SB64 = (NN + 31) / 32;           // 3125

    // ---- layer 0 (dim 32) ----
    spmm_kernel<32, float><<<SB32, 256, 0, stream>>>(x, P1, ent, offsets, cnt, dinv, NN);
    spmm_kernel<32, half_t><<<SB32, 256, 0, stream>>>(P1, P2, ent, offsets, cnt, dinv, NN);
    spmm_kernel<32, half_t><<<SB32, 256, 0, stream>>>(P2, P3, ent, offsets, cnt, dinv, NN);
    fused4_mfma<32, 1><<<MMB, 256, 0, stream>>>(xh, P1, P2, P3, W0, b0, B0, nullptr, NN);

    // ---- layers 1..4 (dim 64) ----
    for (int l = 0; l < 4; ++l) {
        const float* Wl = Ws + (size_t)l * 4 * 64 * 64;
        const float* bl = bs + (size_t)l * 64;
        spmm64_kernel<<<SB64, 256, 0, stream>>>(B0, P1, ent, offsets, cnt, dinv, NN);
        spmm64_kernel<<<SB64, 256, 0, stream>>>(P1, P2, ent, offsets, cnt, dinv, NN);
        spmm64_kernel<<<SB64, 256, 0, stream>>>(P2, P3, ent, offsets, cnt, dinv, NN);
        if (l < 3)
            fused4_mfma<64, 1><<<MMB, 256, 0, stream>>>(B0, P1, P2, P3, Wl, bl, B0, nullptr, NN);
        else
            fused4_mfma<64, 2><<<MMB, 256, 0, stream>>>(B0, P1, P2, P3, Wl, bl, nullptr, out, NN);
    }
}